// Round 2
// baseline (312.522 us; speedup 1.0000x reference)
//
#include <hip/hip_runtime.h>

// Aggregator: out[n, :] = mean over s of features[neighbor_idx[n, s], :]
// features: [200000, 128] fp32, neighbor_idx: [100000, 25] int32,
// out: [100000, 128] fp32.
//
// R2 structure: 2 nodes per wave (half-wave = 32 lanes per node), 16 B/lane
// (float4) gathers -> 512 B per half-wave per sample, fully coalesced.
// Nontemporal store for the streaming output (don't evict feature rows
// from L2); nontemporal load for the single-use indices.

#define N_NODES     100000
#define NUM_SAMPLES 25
#define DIM         128
#define NODES_PER_BLOCK 8   // 4 waves x 2 nodes/wave

typedef float v4f __attribute__((ext_vector_type(4)));

__global__ __launch_bounds__(256) void
Aggregator_45286135169721_kernel(const float* __restrict__ features,
                                 const int* __restrict__ neighbor_idx,
                                 float* __restrict__ out) {
    const int wave = threadIdx.x >> 6;   // 0..3
    const int lane = threadIdx.x & 63;
    const int half = lane >> 5;          // 0 or 1: which node this half-wave owns
    const int sub  = lane & 31;          // lane within half-wave
    const int node = blockIdx.x * NODES_PER_BLOCK + wave * 2 + half;
    if (node >= N_NODES) return;         // grid is exact (12500*8), kept for safety

    const int* __restrict__ row_idx = neighbor_idx + (size_t)node * NUM_SAMPLES;
    const int col = sub * 4;             // each lane owns 4 contiguous columns

    float s0 = 0.0f, s1 = 0.0f, s2 = 0.0f, s3 = 0.0f;
    #pragma unroll
    for (int s = 0; s < NUM_SAMPLES; ++s) {
        const int r = __builtin_nontemporal_load(row_idx + s);  // single-use stream
        const v4f v =
            *reinterpret_cast<const v4f*>(features + (size_t)r * DIM + col);
        s0 += v.x; s1 += v.y; s2 += v.z; s3 += v.w;
    }

    const float inv = 1.0f / (float)NUM_SAMPLES;
    v4f o;
    o.x = s0 * inv; o.y = s1 * inv; o.z = s2 * inv; o.w = s3 * inv;
    // Streaming output: nontemporal so it doesn't displace feature rows in L2.
    __builtin_nontemporal_store(
        o, reinterpret_cast<v4f*>(out + (size_t)node * DIM + col));
}

extern "C" void kernel_launch(void* const* d_in, const int* in_sizes, int n_in,
                              void* d_out, int out_size, void* d_ws, size_t ws_size,
                              hipStream_t stream) {
    const float* features     = (const float*)d_in[0];
    const int*   neighbor_idx = (const int*)d_in[1];
    float*       out          = (float*)d_out;

    const int blocks = (N_NODES + NODES_PER_BLOCK - 1) / NODES_PER_BLOCK; // 12500
    Aggregator_45286135169721_kernel<<<blocks, 256, 0, stream>>>(
        features, neighbor_idx, out);
}